// Round 1
// baseline (3331.325 us; speedup 1.0000x reference)
//
#include <hip/hip_runtime.h>
#include <math.h>

// SRP-PHAT: Ys[bt,d] = sum_{f,p} Xr*cos(w_f*dtau[d,p]) + Xi*sin(w_f*dtau[d,p])
// over the 28 off-diagonal mic pairs (diagonal pairs add a per-bt constant ->
// argmax-invariant, dropped). Output = doas[argmax_d Ys].
//
// M = B*T = 1000, N = D = 2562, K = 513 f-bins x 28 pairs.
// fp32 vector-ALU GEMM, W generated on the fly from taus (1 sincos per elem),
// PHAT normalization fused into the A-tile load. ws holds 3 K-split partials
// of Ys: 3*1000*2562*4 = 30.7 MB.

#define M_TOTAL 1000
#define F_BINS  513
#define D_TOTAL 2562
#define NPAIR   28
#define MT      128
#define NT      128
#define AP      132   // padded A-tile leading dim (16B-aligned, breaks bank conflicts)
#define KSPLIT  3
#define FPS     171   // 513 / 3
#define NMT     8     // ceil(1000/128)
#define NNT     21    // ceil(2562/128)

// off-diagonal pairs of np.triu_indices(8), in p order
__device__ __constant__ int c_ptab[NPAIR] = {1,2,3,4,5,6,7, 9,10,11,12,13,14,
                                             16,17,18,19,20, 22,23,24,25,
                                             27,28,29, 31,32, 34};
__device__ __constant__ int c_i0[NPAIR] = {0,0,0,0,0,0,0, 1,1,1,1,1,1,
                                           2,2,2,2,2, 3,3,3,3, 4,4,4, 5,5, 6};
__device__ __constant__ int c_i1[NPAIR] = {1,2,3,4,5,6,7, 2,3,4,5,6,7,
                                           3,4,5,6,7, 4,5,6,7, 5,6,7, 6,7, 7};

__global__ __launch_bounds__(256, 2) void srp_gemm(
    const float* __restrict__ XXs, const float* __restrict__ taus,
    float* __restrict__ Ys)
{
    __shared__ float sDtau[NPAIR * NT];   // [q][128]
    __shared__ float sWre[NPAIR * NT];    // [q][128]
    __shared__ float sWim[NPAIR * NT];
    __shared__ float sAre[NPAIR * AP];    // [q][132]
    __shared__ float sAim[NPAIR * AP];

    const int tid   = threadIdx.x;
    const int mtile = blockIdx.x;   // 0..7  (bt rows)
    const int ntile = blockIdx.y;   // 0..20 (d cols)
    const int split = blockIdx.z;   // 0..2  (f ranges)
    const int row0  = mtile * MT;
    const int col0  = ntile * NT;
    const int f0    = split * FPS;
    const int tx    = tid & 15;     // 16 col-groups of 8
    const int ty    = tid >> 4;     // 16 row-groups of 8

    // stage dtau[q][dloc] once per block
    for (int e = tid; e < NPAIR * NT; e += 256) {
        int q  = e >> 7;
        int dl = e & 127;
        int dg = col0 + dl;
        if (dg > D_TOTAL - 1) dg = D_TOTAL - 1;   // clamp; stores are guarded
        sDtau[e] = taus[dg * 8 + c_i0[q]] - taus[dg * 8 + c_i1[q]];
    }

    float acc[8][8];
    #pragma unroll
    for (int i = 0; i < 8; ++i)
        #pragma unroll
        for (int j = 0; j < 8; ++j) acc[i][j] = 0.f;

    for (int f = f0; f < f0 + FPS; ++f) {
        __syncthreads();  // dtau ready (iter 0) / previous compute done (iter>0)

        float omega = (float)((double)f * (M_PI / 512.0));  // 2*pi*f/1024

        // W-tile: cos/sin(omega * dtau), [q][128]
        for (int e = tid; e < NPAIR * NT; e += 256) {
            float s, c;
            __sincosf(omega * sDtau[e], &s, &c);
            sWre[e] = c;
            sWim[e] = s;
        }

        // A-tile: gather the 28 off-diag pairs for this f, PHAT-normalize,
        // transpose into [q][row] layout (AP=132 padding: 4-way write conflict max)
        for (int e = tid; e < MT * NPAIR; e += 256) {
            int r  = e / NPAIR;
            int q  = e - r * NPAIR;
            int rg = row0 + r;
            float xr = 0.f, xi = 0.f;
            if (rg < M_TOTAL) {
                const float* bp = XXs + ((size_t)rg * F_BINS + f) * 72;  // (bt*513+f)*2*36
                int p = c_ptab[q];
                xr = bp[p];
                xi = bp[36 + p];
                float mg = sqrtf(xr * xr + xi * xi) + 1e-20f;
                xr /= mg;
                xi /= mg;
            }
            sAre[q * AP + r] = xr;
            sAim[q * AP + r] = xi;
        }
        __syncthreads();

        #pragma unroll 7
        for (int q = 0; q < NPAIR; ++q) {
            float ar[8], ai[8], wr[8], wi[8];
            *(float4*)&ar[0] = *(const float4*)&sAre[q * AP + ty * 8];
            *(float4*)&ar[4] = *(const float4*)&sAre[q * AP + ty * 8 + 4];
            *(float4*)&ai[0] = *(const float4*)&sAim[q * AP + ty * 8];
            *(float4*)&ai[4] = *(const float4*)&sAim[q * AP + ty * 8 + 4];
            *(float4*)&wr[0] = *(const float4*)&sWre[q * NT + tx * 8];
            *(float4*)&wr[4] = *(const float4*)&sWre[q * NT + tx * 8 + 4];
            *(float4*)&wi[0] = *(const float4*)&sWim[q * NT + tx * 8];
            *(float4*)&wi[4] = *(const float4*)&sWim[q * NT + tx * 8 + 4];
            #pragma unroll
            for (int i = 0; i < 8; ++i)
                #pragma unroll
                for (int j = 0; j < 8; ++j)
                    acc[i][j] = fmaf(ar[i], wr[j], fmaf(ai[i], wi[j], acc[i][j]));
        }
    }

    // epilogue: guarded stores into this split's Ys plane
    float* ybase = Ys + (size_t)split * M_TOTAL * D_TOTAL;
    #pragma unroll
    for (int i = 0; i < 8; ++i) {
        int rg = row0 + ty * 8 + i;
        if (rg >= M_TOTAL) continue;
        float* yrow = ybase + (size_t)rg * D_TOTAL;
        #pragma unroll
        for (int j = 0; j < 8; ++j) {
            int cg = col0 + tx * 8 + j;
            if (cg < D_TOTAL) yrow[cg] = acc[i][j];
        }
    }
}

__global__ __launch_bounds__(256) void srp_argmax(
    const float* __restrict__ Ys, const float* __restrict__ doas,
    float* __restrict__ out)
{
    __shared__ float sv[256];
    __shared__ int   si[256];
    const int row = blockIdx.x;
    const int tid = threadIdx.x;
    const float* y0 = Ys + (size_t)row * D_TOTAL;
    const float* y1 = Ys + ((size_t)M_TOTAL + row) * D_TOTAL;
    const float* y2 = Ys + ((size_t)2 * M_TOTAL + row) * D_TOTAL;

    float best = -INFINITY;
    int   bi   = D_TOTAL;
    for (int d = tid; d < D_TOTAL; d += 256) {
        float v = y0[d] + y1[d] + y2[d];
        if (v > best) { best = v; bi = d; }   // strictly-greater keeps first idx
    }
    sv[tid] = best;
    si[tid] = bi;
    __syncthreads();
    for (int s = 128; s > 0; s >>= 1) {
        if (tid < s) {
            float v2 = sv[tid + s];
            int   i2 = si[tid + s];
            if (v2 > sv[tid] || (v2 == sv[tid] && i2 < si[tid])) {
                sv[tid] = v2;
                si[tid] = i2;
            }
        }
        __syncthreads();
    }
    if (tid == 0) {
        int idx = si[0];
        out[row * 3 + 0] = doas[idx * 3 + 0];
        out[row * 3 + 1] = doas[idx * 3 + 1];
        out[row * 3 + 2] = doas[idx * 3 + 2];
    }
}

extern "C" void kernel_launch(void* const* d_in, const int* in_sizes, int n_in,
                              void* d_out, int out_size, void* d_ws, size_t ws_size,
                              hipStream_t stream) {
    const float* XXs  = (const float*)d_in[0];  // (4,250,513,2,36) f32
    const float* taus = (const float*)d_in[1];  // (2562,8) f32
    const float* doas = (const float*)d_in[2];  // (2562,3) f32
    float* Ys = (float*)d_ws;                   // 3 * 1000 * 2562 f32 partials

    dim3 grid(NMT, NNT, KSPLIT);
    srp_gemm<<<grid, 256, 0, stream>>>(XXs, taus, Ys);
    srp_argmax<<<M_TOTAL, 256, 0, stream>>>(Ys, doas, (float*)d_out);
}

// Round 2
// 592.645 us; speedup vs baseline: 5.6211x; 5.6211x over previous
//
#include <hip/hip_runtime.h>
#include <math.h>

// SRP-PHAT via Chebyshev factorization of the steering weights.
// W[d,(f,p)] = cos(w_f * tau_dp), sin(w_f * tau_dp); |tau| <= 4.665, w <= pi
// -> cos(z*u) = sum_{n even} c_n(z) T_n(u), sin(z*u) = sum_{n odd} s_n(z) T_n(u)
//    (Jacobi-Anger; coefficients ~J_n(z), tail ~1e-10 at degree 36)
// Ys[bt,d] = sum_{p,n} G[bt,p,n] * T_n(u_dp),
//   G[bt,p,n] = sum_f Xnorm_{re|im}[bt,f,p] * coef[n][f]   (parity-selected)
// FLOPs: 1.47e11 (direct) -> ~6e9. Diagonal mic pairs dropped (argmax-invariant).

#define F_BINS  513
#define M_TOTAL 1000
#define D_TOTAL 2562
#define D_PAD   2688          // 42 * 64
#define NPAIR   28
#define NC      36            // Chebyshev degree (36 => coeff tail ~1e-10)
#define K2      (NPAIR * NC)  // 1008 = 21 * 48
#define S_SCALE 4.67f         // tau scale bound; z_max = pi*4.67 = 14.67

// ws layout (float offsets); total 6,424,064 floats = 25.7 MB
#define OFF_COEF 0
#define OFF_TT   18560                      // >= 36*513, 16B-aligned
#define OFF_G    (OFF_TT + K2 * D_PAD)      // 2,728,064
#define OFF_YS   (OFF_G + M_TOTAL * K2)     // 3,736,064

__device__ __constant__ int c_ptab[NPAIR] = {1,2,3,4,5,6,7, 9,10,11,12,13,14,
                                             16,17,18,19,20, 22,23,24,25,
                                             27,28,29, 31,32, 34};
__device__ __constant__ int c_i0[NPAIR] = {0,0,0,0,0,0,0, 1,1,1,1,1,1,
                                           2,2,2,2,2, 3,3,3,3, 4,4,4, 5,5, 6};
__device__ __constant__ int c_i1[NPAIR] = {1,2,3,4,5,6,7, 2,3,4,5,6,7,
                                           3,4,5,6,7, 4,5,6,7, 5,6,7, 6,7, 7};

// ---- coefficient generation: Chebyshev interpolation via 36-node DCT -------
// coef[n][f]: n even -> cos-expansion coeff of cos(z_f u); n odd -> sin coeff.
__global__ void k_coef(float* __restrict__ coefC) {
    __shared__ float sHC[NC][NC + 1];
    __shared__ float sHS[NC][NC + 1];
    const int f = blockIdx.x;
    const int t = threadIdx.x;
    const double z = (double)f * (M_PI / 512.0) * (double)S_SCALE;  // w_f * S
    if (t < NC) {
        double th = M_PI * (t + 0.5) / NC;
        double ct = cos(th);
        double hs, hc;
        sincos(z * ct, &hs, &hc);      // h(u_j) at node u_j = cos(th)
        // fill column j=t of h*T_n(u_j) = h*cos(n*th) via recurrence
        double cprev = 1.0, ccur = ct, c2 = 2.0 * ct;
        sHC[0][t] = (float)hc;          sHS[0][t] = (float)hs;
        sHC[1][t] = (float)(hc * ccur); sHS[1][t] = (float)(hs * ccur);
        for (int n = 2; n < NC; ++n) {
            double cn = c2 * ccur - cprev;
            cprev = ccur; ccur = cn;
            sHC[n][t] = (float)(hc * cn);
            sHS[n][t] = (float)(hs * cn);
        }
    }
    __syncthreads();
    if (t < NC) {
        double sum = 0.0;
        if ((t & 1) == 0) { for (int j = 0; j < NC; ++j) sum += (double)sHC[t][j]; }
        else              { for (int j = 0; j < NC; ++j) sum += (double)sHS[t][j]; }
        double scale = (t == 0) ? (1.0 / NC) : (2.0 / NC);
        coefC[t * F_BINS + f] = (float)(sum * scale);
    }
}

// ---- T table: Tt[p*36+n][d] = T_n(tau_dp / S), zero-padded past D_TOTAL ----
__global__ void k_ttab(const float* __restrict__ taus, float* __restrict__ Tt) {
    const int d = blockIdx.x * 256 + threadIdx.x;
    const int p = blockIdx.y;
    if (d >= D_PAD) return;
    const bool live = d < D_TOTAL;
    float u = 0.f;
    if (live) u = (taus[d * 8 + c_i0[p]] - taus[d * 8 + c_i1[p]]) * (1.0f / S_SCALE);
    float t0 = live ? 1.f : 0.f;
    float t1 = live ? u : 0.f;
    float* base = Tt + (size_t)p * NC * D_PAD + d;
    base[0] = t0;
    base[D_PAD] = t1;
    const float u2 = 2.f * u;
    for (int n = 2; n < NC; ++n) {
        float tn = u2 * t1 - t0;
        t0 = t1; t1 = tn;
        base[(size_t)n * D_PAD] = t1;
    }
}

// ---- stage A: G[bt][p*36+n] = sum_f Xnorm * coef[n][f] ---------------------
__global__ __launch_bounds__(256) void k_stageA(
    const float* __restrict__ XXs, const float* __restrict__ coefC,
    float* __restrict__ G)
{
    __shared__ float sXr[NPAIR][132];
    __shared__ float sXi[NPAIR][132];
    __shared__ float sCf[NC][132];
    const int bt = blockIdx.x;
    const int t  = threadIdx.x;
    const int p  = t / 9;        // valid for t < 252
    const int ng = t - p * 9;    // n group: n = ng*4 + i
    float acc0 = 0.f, acc1 = 0.f, acc2 = 0.f, acc3 = 0.f;

    for (int c = 0; c < 5; ++c) {
        const int f0 = c * 128;
        __syncthreads();  // previous chunk's compute done before overwrite
        for (int e = t; e < NC * 128; e += 256) {
            int n = e >> 7, fl = e & 127, f = f0 + fl;
            sCf[n][fl] = (f < F_BINS) ? coefC[n * F_BINS + f] : 0.f;
        }
        for (int e = t; e < 128 * NPAIR; e += 256) {
            int fl = e / NPAIR, q = e - fl * NPAIR;
            int f = f0 + fl;
            float xr = 0.f, xi = 0.f;
            if (f < F_BINS) {
                const float* bp = XXs + ((size_t)bt * F_BINS + f) * 72;
                xr = bp[c_ptab[q]];
                xi = bp[36 + c_ptab[q]];
                float m = sqrtf(xr * xr + xi * xi) + 1e-20f;
                xr /= m; xi /= m;
            }
            sXr[q][fl] = xr;
            sXi[q][fl] = xi;
        }
        __syncthreads();
        if (t < 252) {
            #pragma unroll 8
            for (int fl = 0; fl < 128; fl += 4) {
                float4 xr4 = *(const float4*)&sXr[p][fl];
                float4 xi4 = *(const float4*)&sXi[p][fl];
                float4 c0  = *(const float4*)&sCf[ng * 4 + 0][fl];
                float4 c1  = *(const float4*)&sCf[ng * 4 + 1][fl];
                float4 c2  = *(const float4*)&sCf[ng * 4 + 2][fl];
                float4 c3  = *(const float4*)&sCf[ng * 4 + 3][fl];
                acc0 = fmaf(xr4.x, c0.x, fmaf(xr4.y, c0.y, fmaf(xr4.z, c0.z, fmaf(xr4.w, c0.w, acc0))));
                acc1 = fmaf(xi4.x, c1.x, fmaf(xi4.y, c1.y, fmaf(xi4.z, c1.z, fmaf(xi4.w, c1.w, acc1))));
                acc2 = fmaf(xr4.x, c2.x, fmaf(xr4.y, c2.y, fmaf(xr4.z, c2.z, fmaf(xr4.w, c2.w, acc2))));
                acc3 = fmaf(xi4.x, c3.x, fmaf(xi4.y, c3.y, fmaf(xi4.z, c3.z, fmaf(xi4.w, c3.w, acc3))));
            }
        }
    }
    if (t < 252) {
        float* g = G + (size_t)bt * K2 + p * NC + ng * 4;
        g[0] = acc0; g[1] = acc1; g[2] = acc2; g[3] = acc3;
    }
}

// ---- stage B: Ys[1000][2688] = G[1000][1008] @ Tt[1008][2688] --------------
#define BKB 48
__global__ __launch_bounds__(256) void k_gemmB(
    const float* __restrict__ G, const float* __restrict__ Tt,
    float* __restrict__ Ys)
{
    __shared__ float sA[BKB][68];
    __shared__ float sB[BKB][68];
    const int row0 = blockIdx.x * 64;
    const int col0 = blockIdx.y * 64;
    const int t  = threadIdx.x;
    const int tx = t & 15;
    const int ty = t >> 4;
    float acc[4][4] = {};

    for (int k0 = 0; k0 < K2; k0 += BKB) {
        __syncthreads();
        for (int e = t; e < 64 * BKB; e += 256) {   // A: G[r][k] -> sA[k][r]
            int r = e / BKB, kk = e - r * BKB;
            int rg = row0 + r;
            sA[kk][r] = (rg < M_TOTAL) ? G[(size_t)rg * K2 + k0 + kk] : 0.f;
        }
        for (int e = t; e < 64 * BKB; e += 256) {   // B: Tt[k][c] -> sB[k][c]
            int kk = e >> 6, cc = e & 63;
            sB[kk][cc] = Tt[(size_t)(k0 + kk) * D_PAD + col0 + cc];
        }
        __syncthreads();
        #pragma unroll 6
        for (int kk = 0; kk < BKB; ++kk) {
            float4 a4 = *(const float4*)&sA[kk][ty * 4];
            float4 b4 = *(const float4*)&sB[kk][tx * 4];
            float av[4] = {a4.x, a4.y, a4.z, a4.w};
            float bv[4] = {b4.x, b4.y, b4.z, b4.w};
            #pragma unroll
            for (int i = 0; i < 4; ++i)
                #pragma unroll
                for (int j = 0; j < 4; ++j)
                    acc[i][j] = fmaf(av[i], bv[j], acc[i][j]);
        }
    }
    #pragma unroll
    for (int i = 0; i < 4; ++i) {
        int rg = row0 + ty * 4 + i;
        if (rg >= M_TOTAL) continue;
        float4 v = {acc[i][0], acc[i][1], acc[i][2], acc[i][3]};
        *(float4*)(Ys + (size_t)rg * D_PAD + col0 + tx * 4) = v;
    }
}

// ---- argmax + doa gather ---------------------------------------------------
__global__ __launch_bounds__(256) void k_argmax(
    const float* __restrict__ Ys, const float* __restrict__ doas,
    float* __restrict__ out)
{
    __shared__ float sv[256];
    __shared__ int   si[256];
    const int row = blockIdx.x;
    const int tid = threadIdx.x;
    const float* y = Ys + (size_t)row * D_PAD;
    float best = -INFINITY;
    int bi = D_TOTAL;
    for (int d = tid; d < D_TOTAL; d += 256) {
        float v = y[d];
        if (v > best) { best = v; bi = d; }
    }
    sv[tid] = best; si[tid] = bi;
    __syncthreads();
    for (int s = 128; s > 0; s >>= 1) {
        if (tid < s) {
            float v2 = sv[tid + s]; int i2 = si[tid + s];
            if (v2 > sv[tid] || (v2 == sv[tid] && i2 < si[tid])) { sv[tid] = v2; si[tid] = i2; }
        }
        __syncthreads();
    }
    if (tid == 0) {
        int idx = si[0];
        out[row * 3 + 0] = doas[idx * 3 + 0];
        out[row * 3 + 1] = doas[idx * 3 + 1];
        out[row * 3 + 2] = doas[idx * 3 + 2];
    }
}

extern "C" void kernel_launch(void* const* d_in, const int* in_sizes, int n_in,
                              void* d_out, int out_size, void* d_ws, size_t ws_size,
                              hipStream_t stream) {
    const float* XXs  = (const float*)d_in[0];  // (4,250,513,2,36) f32
    const float* taus = (const float*)d_in[1];  // (2562,8) f32
    const float* doas = (const float*)d_in[2];  // (2562,3) f32
    float* ws    = (float*)d_ws;
    float* coefC = ws + OFF_COEF;
    float* Tt    = ws + OFF_TT;
    float* G     = ws + OFF_G;
    float* Ys    = ws + OFF_YS;

    k_coef  <<<F_BINS, 64, 0, stream>>>(coefC);
    k_ttab  <<<dim3((D_PAD + 255) / 256, NPAIR), 256, 0, stream>>>(taus, Tt);
    k_stageA<<<M_TOTAL, 256, 0, stream>>>(XXs, coefC, G);
    k_gemmB <<<dim3(16, 42), 256, 0, stream>>>(G, Tt, Ys);
    k_argmax<<<M_TOTAL, 256, 0, stream>>>(Ys, doas, (float*)d_out);
}

// Round 3
// 420.627 us; speedup vs baseline: 7.9199x; 1.4090x over previous
//
#include <hip/hip_runtime.h>
#include <math.h>

// SRP-PHAT via Chebyshev factorization (degree 32; tail ~1e-7 at z_max=14.67).
// G[bt, p*32+c] = sum_f Xnorm_{re|im}[bt,f,p] * coef_c(w_f*S)   (c<16: even n=2c
//   with Xr; c>=16: odd n=2(c-16)+1 with Xi), then
// Ys[bt,d] = sum_k G[bt,k] * Tt[k,d],  Tt[p*32+c, d] = T_n(dtau_dp/S).
// Diagonal mic pairs dropped (constant per bt -> argmax-invariant).

#define F_BINS  513
#define M_TOTAL 1000
#define D_TOTAL 2562
#define D_PAD   2688          // 21 * 128
#define NPAIR   28
#define NC      32
#define K2      (NPAIR * NC)  // 896
#define S_SCALE 4.67f         // |dtau| <= 4.665
#define FSPLIT  4
#define FCHUNK  129           // ceil(513/4)

// ws layout (float offsets), total 6,904,960 floats = 27.6 MB.
// Ys aliases Gp (Gp fully consumed by k_reduceG before k_gemmB writes Ys).
#define OFF_COEF 0
#define OFF_TT   16512
#define OFF_GP   (OFF_TT + (size_t)K2 * D_PAD)        // 2,424,960
#define OFF_YS   OFF_GP
#define OFF_G    (OFF_GP + (size_t)4 * M_TOTAL * K2)  // 6,008,960

__device__ __constant__ int c_ptab[NPAIR] = {1,2,3,4,5,6,7, 9,10,11,12,13,14,
                                             16,17,18,19,20, 22,23,24,25,
                                             27,28,29, 31,32, 34};
__device__ __constant__ int c_i0[NPAIR] = {0,0,0,0,0,0,0, 1,1,1,1,1,1,
                                           2,2,2,2,2, 3,3,3,3, 4,4,4, 5,5, 6};
__device__ __constant__ int c_i1[NPAIR] = {1,2,3,4,5,6,7, 2,3,4,5,6,7,
                                           3,4,5,6,7, 4,5,6,7, 5,6,7, 6,7, 7};

// ---- coefEO[f][32]: c<16 -> cos-coeff a_{2c}(z_f); c>=16 -> sin b_{2c'+1} ---
__global__ void k_coef(float* __restrict__ coefEO) {
    __shared__ double sHC[NC][NC + 1];
    __shared__ double sHS[NC][NC + 1];
    const int f = blockIdx.x;
    const int t = threadIdx.x;          // 32 threads
    const double z = (double)f * (M_PI / 512.0) * (double)S_SCALE;
    double th = M_PI * (t + 0.5) / NC;
    double ct = cos(th);
    double hs, hc;
    sincos(z * ct, &hs, &hc);
    double cp = 1.0, cc = ct, c2 = 2.0 * ct;
    sHC[0][t] = hc;      sHS[0][t] = hs;
    sHC[1][t] = hc * cc; sHS[1][t] = hs * cc;
    for (int n = 2; n < NC; ++n) {
        double cn = c2 * cc - cp;
        cp = cc; cc = cn;
        sHC[n][t] = hc * cn;
        sHS[n][t] = hs * cn;
    }
    __syncthreads();
    const int n = (t < 16) ? 2 * t : 2 * (t - 16) + 1;
    double sum = 0.0;
    if (t < 16) { for (int j = 0; j < NC; ++j) sum += sHC[n][j]; }
    else        { for (int j = 0; j < NC; ++j) sum += sHS[n][j]; }
    double scale = (n == 0) ? (1.0 / NC) : (2.0 / NC);
    coefEO[f * 32 + t] = (float)(sum * scale);
}

// ---- Tt[p*32+c][d]: c<16 -> T_{2c}(u), c>=16 -> T_{2(c-16)+1}(u) -----------
__global__ void k_ttab(const float* __restrict__ taus, float* __restrict__ Tt) {
    const int d = blockIdx.x * 256 + threadIdx.x;
    const int p = blockIdx.y;
    if (d >= D_PAD) return;
    const bool live = d < D_TOTAL;
    const int dd = live ? d : 0;
    const float u = (taus[dd * 8 + c_i0[p]] - taus[dd * 8 + c_i1[p]]) * (1.0f / S_SCALE);
    float* base = Tt + (size_t)p * 32 * D_PAD + d;
    base[0] = live ? 1.f : 0.f;                       // n=0 -> c=0
    base[(size_t)16 * D_PAD] = live ? u : 0.f;        // n=1 -> c=16
    float tp = 1.f, tc = u;
    const float u2 = 2.f * u;
    for (int n = 2; n < NC; ++n) {
        float tn = u2 * tc - tp;
        tp = tc; tc = tn;
        int c = (n & 1) ? 16 + (n >> 1) : (n >> 1);
        base[(size_t)c * D_PAD] = live ? tn : 0.f;
    }
}

// ---- stage A: Gp[split][bt][p*32+c], 8 bt x 224 rows x 32 n per block ------
__global__ __launch_bounds__(256) void k_stageA(
    const float* __restrict__ XXs, const float* __restrict__ coefEO,
    float* __restrict__ Gp)
{
    __shared__ float sXr[16][224];
    __shared__ float sXi[16][224];
    __shared__ float sC[16][32];
    const int t     = threadIdx.x;
    const int bt0   = blockIdx.x * 8;
    const int split = blockIdx.y;
    const int fbeg  = split * FCHUNK;
    const int fend  = min(F_BINS, fbeg + FCHUNK);
    const int rg = t % 56;       // row group (4 rows)
    const int ng = t / 56;       // 0..3 (t<224 active); 0,1 -> Xr, 2,3 -> Xi
    const int sp  = t % 28;      // staging pair
    const int sbt = t / 28;      // staging bt (t<224)
    const float* xbase = XXs + (size_t)(bt0 + sbt) * F_BINS * 72;
    const int p_off = c_ptab[sp];

    float acc[4][8] = {};

    for (int fc = fbeg; fc < fend; fc += 16) {
        const int cnt = min(16, fend - fc);
        __syncthreads();   // previous chunk consumed
        for (int e = t; e < 512; e += 256) {
            int fl = e >> 5, c = e & 31;
            sC[fl][c] = (fl < cnt) ? coefEO[(fc + fl) * 32 + c] : 0.f;
        }
        if (t < 224) {
            for (int fl = 0; fl < cnt; ++fl) {
                const float* bp = xbase + (size_t)(fc + fl) * 72;
                float xr = bp[p_off];
                float xi = bp[36 + p_off];
                float inv = 1.f / (sqrtf(xr * xr + xi * xi) + 1e-20f);
                sXr[fl][t] = xr * inv;
                sXi[fl][t] = xi * inv;
            }
        }
        __syncthreads();
        if (t < 224) {
            const float (*sX)[224] = (ng < 2) ? sXr : sXi;
            for (int fl = 0; fl < cnt; ++fl) {
                float4 x4 = *(const float4*)&sX[fl][rg * 4];
                float4 c0 = *(const float4*)&sC[fl][ng * 8];
                float4 c1 = *(const float4*)&sC[fl][ng * 8 + 4];
                float xv[4] = {x4.x, x4.y, x4.z, x4.w};
                float cv[8] = {c0.x, c0.y, c0.z, c0.w, c1.x, c1.y, c1.z, c1.w};
                #pragma unroll
                for (int i = 0; i < 4; ++i)
                    #pragma unroll
                    for (int j = 0; j < 8; ++j)
                        acc[i][j] = fmaf(xv[i], cv[j], acc[i][j]);
            }
        }
    }

    if (t < 224) {
        float* gsp = Gp + (size_t)split * M_TOTAL * K2;
        #pragma unroll
        for (int i = 0; i < 4; ++i) {
            int r   = rg * 4 + i;
            int btl = r / 28;
            int pp  = r - btl * 28;
            float* g = gsp + (size_t)(bt0 + btl) * K2 + pp * 32 + ng * 8;
            float4 v0 = {acc[i][0], acc[i][1], acc[i][2], acc[i][3]};
            float4 v1 = {acc[i][4], acc[i][5], acc[i][6], acc[i][7]};
            *(float4*)&g[0] = v0;
            *(float4*)&g[4] = v1;
        }
    }
}

// ---- reduce the 4 f-split partials ----------------------------------------
__global__ void k_reduceG(const float* __restrict__ Gp, float* __restrict__ G) {
    const int i = blockIdx.x * 256 + threadIdx.x;
    const size_t MK = (size_t)M_TOTAL * K2;
    if (i < (int)MK)
        G[i] = (Gp[i] + Gp[i + MK]) + (Gp[i + 2 * MK] + Gp[i + 3 * MK]);
}

// ---- stage B: Ys[1000][2688] = G[1000][896] @ Tt[896][2688] ----------------
#define BKB 32
__global__ __launch_bounds__(256) void k_gemmB(
    const float* __restrict__ G, const float* __restrict__ Tt,
    float* __restrict__ Ys)
{
    __shared__ float sA[BKB][68];
    __shared__ float sB[BKB][132];
    const int t = threadIdx.x;
    const int row0 = blockIdx.x * 64;
    const int col0 = blockIdx.y * 128;
    const int tx = t & 15;
    const int ty = t >> 4;
    float acc[4][8] = {};

    for (int k0 = 0; k0 < K2; k0 += BKB) {
        __syncthreads();
        for (int e = t; e < 64 * BKB; e += 256) {   // A: G[r][k] -> sA[k][r]
            int r = e >> 5, kk = e & 31;
            int rgl = row0 + r;
            sA[kk][r] = (rgl < M_TOTAL) ? G[(size_t)rgl * K2 + k0 + kk] : 0.f;
        }
        for (int e = t; e < 1024; e += 256) {       // B: 32x128, float4
            int kk = e >> 5, c = (e & 31) * 4;
            *(float4*)&sB[kk][c] =
                *(const float4*)&Tt[(size_t)(k0 + kk) * D_PAD + col0 + c];
        }
        __syncthreads();
        #pragma unroll 8
        for (int kk = 0; kk < BKB; ++kk) {
            float4 a4 = *(const float4*)&sA[kk][ty * 4];
            float4 b0 = *(const float4*)&sB[kk][tx * 8];
            float4 b1 = *(const float4*)&sB[kk][tx * 8 + 4];
            float av[4] = {a4.x, a4.y, a4.z, a4.w};
            float bv[8] = {b0.x, b0.y, b0.z, b0.w, b1.x, b1.y, b1.z, b1.w};
            #pragma unroll
            for (int i = 0; i < 4; ++i)
                #pragma unroll
                for (int j = 0; j < 8; ++j)
                    acc[i][j] = fmaf(av[i], bv[j], acc[i][j]);
        }
    }
    #pragma unroll
    for (int i = 0; i < 4; ++i) {
        int rgl = row0 + ty * 4 + i;
        if (rgl >= M_TOTAL) continue;
        float* y = Ys + (size_t)rgl * D_PAD + col0 + tx * 8;
        float4 v0 = {acc[i][0], acc[i][1], acc[i][2], acc[i][3]};
        float4 v1 = {acc[i][4], acc[i][5], acc[i][6], acc[i][7]};
        *(float4*)&y[0] = v0;
        *(float4*)&y[4] = v1;
    }
}

// ---- argmax + doa gather ---------------------------------------------------
__global__ __launch_bounds__(256) void k_argmax(
    const float* __restrict__ Ys, const float* __restrict__ doas,
    float* __restrict__ out)
{
    __shared__ float sv[256];
    __shared__ int   si[256];
    const int row = blockIdx.x;
    const int tid = threadIdx.x;
    const float* y = Ys + (size_t)row * D_PAD;
    float best = -INFINITY;
    int bi = D_TOTAL;
    for (int d = tid; d < D_TOTAL; d += 256) {
        float v = y[d];
        if (v > best) { best = v; bi = d; }
    }
    sv[tid] = best; si[tid] = bi;
    __syncthreads();
    for (int s = 128; s > 0; s >>= 1) {
        if (tid < s) {
            float v2 = sv[tid + s]; int i2 = si[tid + s];
            if (v2 > sv[tid] || (v2 == sv[tid] && i2 < si[tid])) { sv[tid] = v2; si[tid] = i2; }
        }
        __syncthreads();
    }
    if (tid == 0) {
        int idx = si[0];
        out[row * 3 + 0] = doas[idx * 3 + 0];
        out[row * 3 + 1] = doas[idx * 3 + 1];
        out[row * 3 + 2] = doas[idx * 3 + 2];
    }
}

extern "C" void kernel_launch(void* const* d_in, const int* in_sizes, int n_in,
                              void* d_out, int out_size, void* d_ws, size_t ws_size,
                              hipStream_t stream) {
    const float* XXs  = (const float*)d_in[0];  // (4,250,513,2,36) f32
    const float* taus = (const float*)d_in[1];  // (2562,8) f32
    const float* doas = (const float*)d_in[2];  // (2562,3) f32
    float* ws     = (float*)d_ws;
    float* coefEO = ws + OFF_COEF;
    float* Tt     = ws + OFF_TT;
    float* Gp     = ws + OFF_GP;
    float* G      = ws + OFF_G;
    float* Ys     = ws + OFF_YS;   // aliases Gp (safe: Gp consumed by k_reduceG)

    k_coef   <<<F_BINS, 32, 0, stream>>>(coefEO);
    k_ttab   <<<dim3((D_PAD + 255) / 256, NPAIR), 256, 0, stream>>>(taus, Tt);
    k_stageA <<<dim3(M_TOTAL / 8, FSPLIT), 256, 0, stream>>>(XXs, coefEO, Gp);
    k_reduceG<<<(M_TOTAL * K2 + 255) / 256, 256, 0, stream>>>(Gp, G);
    k_gemmB  <<<dim3(16, D_PAD / 128), 256, 0, stream>>>(G, Tt, Ys);
    k_argmax <<<M_TOTAL, 256, 0, stream>>>(Ys, doas, (float*)d_out);
}

// Round 4
// 354.956 us; speedup vs baseline: 9.3852x; 1.1850x over previous
//
#include <hip/hip_runtime.h>
#include <math.h>

// SRP-PHAT via Chebyshev factorization (degree 32; tail ~1e-7 at z_max=14.67).
// G[bt, p*32+c] = sum_f Xnorm_{re|im}[bt,f,p] * coef_c(w_f*S)   (c<16: even n=2c
//   with Xr; c>=16: odd n with Xi), then Ys[bt,d] = sum_k G[bt,k]*Tt[k,d].
// Diagonal mic pairs dropped (constant per bt -> argmax-invariant).
// Round 4: stageA = 1000 blocks (coalesced raw staging, normalize in LDS);
// gemmB = 64x64 tiles, K-split x2 (1344 blocks), conflict-free sAT[64][33].

#define F_BINS  513
#define M_TOTAL 1000
#define D_TOTAL 2562
#define D_PAD   2688          // 42 * 64
#define NPAIR   28
#define NC      32
#define K2      (NPAIR * NC)  // 896
#define S_SCALE 4.67f         // |dtau| <= 4.665
#define KSPB    2             // gemmB K-splits
#define KPS     448           // K2 / KSPB

// ws layout (float offsets); total 8,696,960 floats = 34.8 MB
#define OFF_COEF 0
#define OFF_TT   16512
#define OFF_G    (OFF_TT + (size_t)K2 * D_PAD)          // 2,424,960
#define OFF_YS   (OFF_G + (size_t)M_TOTAL * K2)         // 3,320,960  (2 planes)

__device__ __constant__ int c_ptab[NPAIR] = {1,2,3,4,5,6,7, 9,10,11,12,13,14,
                                             16,17,18,19,20, 22,23,24,25,
                                             27,28,29, 31,32, 34};
__device__ __constant__ int c_i0[NPAIR] = {0,0,0,0,0,0,0, 1,1,1,1,1,1,
                                           2,2,2,2,2, 3,3,3,3, 4,4,4, 5,5, 6};
__device__ __constant__ int c_i1[NPAIR] = {1,2,3,4,5,6,7, 2,3,4,5,6,7,
                                           3,4,5,6,7, 4,5,6,7, 5,6,7, 6,7, 7};

// ---- coefEO[f][32]: c<16 -> cos-coeff a_{2c}(z_f); c>=16 -> sin b_{2c'+1} ---
__global__ void k_coef(float* __restrict__ coefEO) {
    __shared__ double sHC[NC][NC + 1];
    __shared__ double sHS[NC][NC + 1];
    const int f = blockIdx.x;
    const int t = threadIdx.x;          // 32 threads
    const double z = (double)f * (M_PI / 512.0) * (double)S_SCALE;
    double th = M_PI * (t + 0.5) / NC;
    double ct = cos(th);
    double hs, hc;
    sincos(z * ct, &hs, &hc);
    double cp = 1.0, cc = ct, c2 = 2.0 * ct;
    sHC[0][t] = hc;      sHS[0][t] = hs;
    sHC[1][t] = hc * cc; sHS[1][t] = hs * cc;
    for (int n = 2; n < NC; ++n) {
        double cn = c2 * cc - cp;
        cp = cc; cc = cn;
        sHC[n][t] = hc * cn;
        sHS[n][t] = hs * cn;
    }
    __syncthreads();
    const int n = (t < 16) ? 2 * t : 2 * (t - 16) + 1;
    double sum = 0.0;
    if (t < 16) { for (int j = 0; j < NC; ++j) sum += sHC[n][j]; }
    else        { for (int j = 0; j < NC; ++j) sum += sHS[n][j]; }
    double scale = (n == 0) ? (1.0 / NC) : (2.0 / NC);
    coefEO[f * 32 + t] = (float)(sum * scale);
}

// ---- Tt[p*32+c][d]: c<16 -> T_{2c}(u), c>=16 -> T_{2(c-16)+1}(u) -----------
__global__ void k_ttab(const float* __restrict__ taus, float* __restrict__ Tt) {
    const int d = blockIdx.x * 256 + threadIdx.x;
    const int p = blockIdx.y;
    if (d >= D_PAD) return;
    const bool live = d < D_TOTAL;
    const int dd = live ? d : 0;
    const float u = (taus[dd * 8 + c_i0[p]] - taus[dd * 8 + c_i1[p]]) * (1.0f / S_SCALE);
    float* base = Tt + (size_t)p * 32 * D_PAD + d;
    base[0] = live ? 1.f : 0.f;                       // n=0 -> c=0
    base[(size_t)16 * D_PAD] = live ? u : 0.f;        // n=1 -> c=16
    float tp = 1.f, tc = u;
    const float u2 = 2.f * u;
    for (int n = 2; n < NC; ++n) {
        float tn = u2 * tc - tp;
        tp = tc; tc = tn;
        int c = (n & 1) ? 16 + (n >> 1) : (n >> 1);
        base[(size_t)c * D_PAD] = live ? tn : 0.f;
    }
}

// ---- stage A: one bt per block. G[bt][p*32+c] -------------------------------
// thread t: p = t&31 (pairs; p>=28 dead), sel = t>>5: sel<4 -> Xr, c0=sel*4;
// sel>=4 -> Xi, c0=16+(sel-4)*4. 4 accumulators per thread.
__global__ __launch_bounds__(256) void k_stageA(
    const float* __restrict__ XXs, const float* __restrict__ coefEO,
    float* __restrict__ G)
{
    __shared__ float sRaw[32][72];   // raw X rows for 32 f        (9216 B)
    __shared__ float sXn[32][64];    // [f][row: re 0..27, im 32..59] (8192 B)
    __shared__ float sC[32][32];     // coef chunk                 (4096 B)
    const int bt = blockIdx.x;
    const int t  = threadIdx.x;
    const int p   = t & 31;
    const int sel = t >> 5;
    const bool im = sel >= 4;
    const int row = p + (im ? 32 : 0);
    const int c0  = (sel & 3) * 4 + (im ? 16 : 0);
    const float* xb = XXs + (size_t)bt * F_BINS * 72;
    float acc[4] = {};

    for (int f0 = 0; f0 < F_BINS; f0 += 32) {
        const int cnt = min(32, F_BINS - f0);
        __syncthreads();   // previous chunk consumed
        for (int e = t; e < cnt * 8; e += 256)      // coef, float4-coalesced
            *(float4*)&sC[0][e * 4] = *(const float4*)&coefEO[f0 * 32 + e * 4];
        for (int e = t; e < cnt * 18; e += 256) {   // raw X, float4-coalesced
            int fl = e / 18, q = e - fl * 18;
            *(float4*)&sRaw[fl][q * 4] = *(const float4*)&xb[(size_t)(f0 + fl) * 72 + q * 4];
        }
        __syncthreads();
        for (int e = t; e < cnt * 28; e += 256) {   // PHAT-normalize in LDS
            int fl = e / 28, pp = e - fl * 28;
            int po = c_ptab[pp];
            float xr = sRaw[fl][po];
            float xi = sRaw[fl][36 + po];
            float inv = 1.f / (sqrtf(xr * xr + xi * xi) + 1e-20f);
            sXn[fl][pp]      = xr * inv;
            sXn[fl][32 + pp] = xi * inv;
        }
        __syncthreads();
        for (int fl = 0; fl < cnt; ++fl) {
            float a = sXn[fl][row];                     // conflict-free b32
            float4 c4 = *(const float4*)&sC[fl][c0];    // 2-addr broadcast b128
            acc[0] = fmaf(a, c4.x, acc[0]);
            acc[1] = fmaf(a, c4.y, acc[1]);
            acc[2] = fmaf(a, c4.z, acc[2]);
            acc[3] = fmaf(a, c4.w, acc[3]);
        }
    }
    if (p < NPAIR) {
        float4 v = {acc[0], acc[1], acc[2], acc[3]};
        *(float4*)&G[(size_t)bt * K2 + p * 32 + c0] = v;
    }
}

// ---- stage B: Ysp[split][1000][2688] partial of G @ Tt ---------------------
#define BKB 32
__global__ __launch_bounds__(256) void k_gemmB(
    const float* __restrict__ G, const float* __restrict__ Tt,
    float* __restrict__ Ysp)
{
    __shared__ float sAT[64][33];    // [row][k] — conflict-free both sides
    __shared__ float sB[BKB][68];
    const int t = threadIdx.x;
    const int row0  = blockIdx.x * 64;
    const int col0  = blockIdx.y * 64;
    const int koff  = blockIdx.z * KPS;
    const int tx = t & 15;
    const int ty = t >> 4;
    float acc[4][4] = {};

    for (int k0 = 0; k0 < KPS; k0 += BKB) {
        __syncthreads();
        for (int e = t; e < 64 * BKB; e += 256) {   // A: coalesced read, cf write
            int r = e >> 5, kk = e & 31;
            int rg = row0 + r;
            sAT[r][kk] = (rg < M_TOTAL) ? G[(size_t)rg * K2 + koff + k0 + kk] : 0.f;
        }
        for (int e = t; e < 512; e += 256) {        // B: 32x64 float4
            int kk = e >> 4, cq = e & 15;
            *(float4*)&sB[kk][cq * 4] =
                *(const float4*)&Tt[(size_t)(koff + k0 + kk) * D_PAD + col0 + cq * 4];
        }
        __syncthreads();
        #pragma unroll 8
        for (int kk = 0; kk < BKB; ++kk) {
            float a0 = sAT[ty * 4 + 0][kk];
            float a1 = sAT[ty * 4 + 1][kk];
            float a2 = sAT[ty * 4 + 2][kk];
            float a3 = sAT[ty * 4 + 3][kk];
            float4 b = *(const float4*)&sB[kk][tx * 4];
            float av[4] = {a0, a1, a2, a3};
            float bv[4] = {b.x, b.y, b.z, b.w};
            #pragma unroll
            for (int i = 0; i < 4; ++i)
                #pragma unroll
                for (int j = 0; j < 4; ++j)
                    acc[i][j] = fmaf(av[i], bv[j], acc[i][j]);
        }
    }
    float* yp = Ysp + (size_t)blockIdx.z * M_TOTAL * D_PAD;
    #pragma unroll
    for (int i = 0; i < 4; ++i) {
        int rg = row0 + ty * 4 + i;
        if (rg >= M_TOTAL) continue;
        float4 v = {acc[i][0], acc[i][1], acc[i][2], acc[i][3]};
        *(float4*)(yp + (size_t)rg * D_PAD + col0 + tx * 4) = v;
    }
}

// ---- argmax over summed K-split partials + doa gather ----------------------
__global__ __launch_bounds__(256) void k_argmax(
    const float* __restrict__ Ysp, const float* __restrict__ doas,
    float* __restrict__ out)
{
    __shared__ float sv[256];
    __shared__ int   si[256];
    const int row = blockIdx.x;
    const int tid = threadIdx.x;
    const float* y0 = Ysp + (size_t)row * D_PAD;
    const float* y1 = y0 + (size_t)M_TOTAL * D_PAD;
    float best = -INFINITY;
    int bi = D_TOTAL;
    for (int d = tid; d < D_TOTAL; d += 256) {
        float v = y0[d] + y1[d];
        if (v > best) { best = v; bi = d; }
    }
    sv[tid] = best; si[tid] = bi;
    __syncthreads();
    for (int s = 128; s > 0; s >>= 1) {
        if (tid < s) {
            float v2 = sv[tid + s]; int i2 = si[tid + s];
            if (v2 > sv[tid] || (v2 == sv[tid] && i2 < si[tid])) { sv[tid] = v2; si[tid] = i2; }
        }
        __syncthreads();
    }
    if (tid == 0) {
        int idx = si[0];
        out[row * 3 + 0] = doas[idx * 3 + 0];
        out[row * 3 + 1] = doas[idx * 3 + 1];
        out[row * 3 + 2] = doas[idx * 3 + 2];
    }
}

extern "C" void kernel_launch(void* const* d_in, const int* in_sizes, int n_in,
                              void* d_out, int out_size, void* d_ws, size_t ws_size,
                              hipStream_t stream) {
    const float* XXs  = (const float*)d_in[0];  // (4,250,513,2,36) f32
    const float* taus = (const float*)d_in[1];  // (2562,8) f32
    const float* doas = (const float*)d_in[2];  // (2562,3) f32
    float* ws     = (float*)d_ws;
    float* coefEO = ws + OFF_COEF;
    float* Tt     = ws + OFF_TT;
    float* G      = ws + OFF_G;
    float* Ysp    = ws + OFF_YS;

    k_coef  <<<F_BINS, 32, 0, stream>>>(coefEO);
    k_ttab  <<<dim3((D_PAD + 255) / 256, NPAIR), 256, 0, stream>>>(taus, Tt);
    k_stageA<<<M_TOTAL, 256, 0, stream>>>(XXs, coefEO, G);
    k_gemmB <<<dim3(16, D_PAD / 64, KSPB), 256, 0, stream>>>(G, Tt, Ysp);
    k_argmax<<<M_TOTAL, 256, 0, stream>>>(Ysp, doas, (float*)d_out);
}